// Round 5
// baseline (557.040 us; speedup 1.0000x reference)
//
#include <hip/hip_runtime.h>
#include <math.h>

// S4D forward (conv mode) via chunked linear recurrence, packed-fp32 math.
// y[b,l,d] = D[d]*x[b,l,d] + sum_n CB[d,n] * h_n[l],  h_n[l] = a_n h_n[l-1] + x[l]
// a = exp(dt*A), CB = C * expm1(dt*A)/A * B, A_n = -0.5*(n+1)
//
// States packed in n-pairs -> v_pk_fma_f32 (2 fp32 FMA/cyc/lane, the only
// path to the 157 TF fp32 rate). No pins, no launch-bound caps, no LDS:
// t-tile = 8 keeps the live set ~105 VGPR so any allocator choice is cheap.
// P0 coef:  acb4[n2][d] = {a0,a1,cb0,cb1} fp32; a2t[n2][d]={a0,a1}; aT[n][d].
// P1 state: chunk-local end states (zero init), h2[32] packed, u bf16.
// P2 scan:  s[c+1] = aT*s[c] + u[c] over 32 chunks, bf16 in/out, fp32 carry.
// P3 out:   h2 init = s_start(bf16), packed recurrence + cb-dot + D-skip.

typedef float v2f __attribute__((ext_vector_type(2)));

namespace {
constexpr int kBatch = 8;
constexpr int kLen   = 2048;
constexpr int kD     = 1024;
constexpr int kN     = 64;         // states
constexpr int kN2    = kN / 2;     // packed pairs
constexpr int kT     = 64;         // chunk length
constexpr int kTT    = 8;          // t-tile
constexpr int kC     = kLen / kT;  // 32 chunks

constexpr long kUElems = (long)kBatch * kC * kN * kD;  // 16,777,216 bf16
constexpr long kUBytes = kUElems * 2;                  // 33,554,432 B
// ws layout: u bf16 | acb4 float4[kN2*kD] | a2t float2[kN2*kD] | aT float[kN*kD]
}  // namespace

__device__ __forceinline__ unsigned short f2bf(float f) {
  unsigned u = __builtin_bit_cast(unsigned, f);
  u += 0x7fffu + ((u >> 16) & 1u);  // round-nearest-even
  return (unsigned short)(u >> 16);
}
__device__ __forceinline__ float bf2f(unsigned short h) {
  unsigned u = ((unsigned)h) << 16;
  return __builtin_bit_cast(float, u);
}
__device__ __forceinline__ v2f pkfma(v2f a, v2f b, v2f c) {
  return __builtin_elementwise_fma(a, b, c);
}

__global__ void s4d_coef_kernel(const float* __restrict__ log_dt,
                                const float* __restrict__ Bm,
                                const float* __restrict__ Cm,
                                float4* __restrict__ acb4,
                                float2* __restrict__ a2t,
                                float* __restrict__ aTt) {
  int tid = blockIdx.x * blockDim.x + threadIdx.x;  // 32768 threads
  int d  = tid & (kD - 1);
  int n2 = tid >> 10;
  float dt = expf(log_dt[d]);
  float a[2], cb[2];
#pragma unroll
  for (int j = 0; j < 2; ++j) {
    int n = 2 * n2 + j;
    float An  = -0.5f * (float)(n + 1);
    float dtA = dt * An;
    a[j] = expf(dtA);
    float bbar = (expm1f(dtA) / An) * Bm[d * kN + n];
    cb[j] = Cm[d * kN + n] * bbar;
    aTt[(long)n * kD + d] = expf(dtA * (float)kT);  // a^64
  }
  acb4[(long)n2 * kD + d] = make_float4(a[0], a[1], cb[0], cb[1]);
  a2t[(long)n2 * kD + d]  = make_float2(a[0], a[1]);
}

// Phase 1: chunk-local end states only (zero initial state).
__global__ __launch_bounds__(256) void s4d_state_kernel(
    const float* __restrict__ x, const float2* __restrict__ a2t,
    unsigned short* __restrict__ u) {
  int tid = blockIdx.x * blockDim.x + threadIdx.x;  // 262144 threads
  int d  = tid & (kD - 1);   // consecutive lanes -> consecutive d: coalesced
  int bc = tid >> 10;
  int b  = bc >> 5;
  int c  = bc & (kC - 1);

  const float* xp = x + ((long)b * kLen + (long)c * kT) * kD + d;
  const float2* ap = a2t + d;

  v2f h2[kN2];
#pragma unroll
  for (int n = 0; n < kN2; ++n) h2[n] = (v2f)0.f;

#pragma unroll 1
  for (int tt = 0; tt < kT / kTT; ++tt) {
    float xv[kTT];
#pragma unroll
    for (int t = 0; t < kTT; ++t) xv[t] = xp[(long)(tt * kTT + t) * kD];
#pragma unroll 8
    for (int n = 0; n < kN2; ++n) {
      float2 af = ap[(long)n * kD];
      v2f a2 = {af.x, af.y};
      v2f hn = h2[n];
#pragma unroll
      for (int t = 0; t < kTT; ++t) {
        v2f xx = {xv[t], xv[t]};
        hn = pkfma(hn, a2, xx);
      }
      h2[n] = hn;
    }
  }
  unsigned short* up = u + ((long)(b * kC + c) * kN) * kD + d;
#pragma unroll
  for (int n = 0; n < kN2; ++n) {
    up[(long)(2 * n) * kD]     = f2bf(h2[n].x);
    up[(long)(2 * n + 1) * kD] = f2bf(h2[n].y);
  }
}

// Phase 2: inter-chunk scan. After this the u-region holds s_start[c] =
// state at the END of chunk c-1 (initial state for chunk c), bf16.
__global__ void s4d_scan_kernel(const float* __restrict__ aTt,
                                unsigned short* __restrict__ u) {
  int tid = blockIdx.x * blockDim.x + threadIdx.x;  // 524288 threads
  int d  = tid & (kD - 1);
  int bn = tid >> 10;
  int n  = bn & (kN - 1);
  int b  = bn >> 6;
  float aT = aTt[(long)n * kD + d];
  unsigned short* up = u + ((long)b * kC * kN + n) * kD + d;
  const long cs = (long)kN * kD;
  float s = 0.f;
#pragma unroll 1
  for (int c = 0; c < kC; ++c) {
    float uv = bf2f(up[(long)c * cs]);
    up[(long)c * cs] = f2bf(s);  // in place: u[c] -> s_start[c]
    s = fmaf(aT, s, uv);
  }
}

// Phase 3: full output. Recurrence with scanned initial state, y written once.
__global__ __launch_bounds__(256) void s4d_out_kernel(
    const float* __restrict__ x, const float* __restrict__ Dv,
    const float4* __restrict__ acb4, const unsigned short* __restrict__ u,
    float* __restrict__ y) {
  int tid = blockIdx.x * blockDim.x + threadIdx.x;  // 262144 threads
  int d  = tid & (kD - 1);
  int bc = tid >> 10;
  int b  = bc >> 5;
  int c  = bc & (kC - 1);

  const unsigned short* sp = u + ((long)(b * kC + c) * kN) * kD + d;
  v2f h2[kN2];
#pragma unroll
  for (int n = 0; n < kN2; ++n) {
    v2f t = {bf2f(sp[(long)(2 * n) * kD]), bf2f(sp[(long)(2 * n + 1) * kD])};
    h2[n] = t;
  }

  float Dd = Dv[d];
  const float*  xp = x + ((long)b * kLen + (long)c * kT) * kD + d;
  float*        yp = y + ((long)b * kLen + (long)c * kT) * kD + d;
  const float4* ap = acb4 + d;

#pragma unroll 1
  for (int tt = 0; tt < kT / kTT; ++tt) {
    float xv[kTT];
#pragma unroll
    for (int t = 0; t < kTT; ++t) xv[t] = xp[(long)(tt * kTT + t) * kD];
    v2f acc2[kTT];
#pragma unroll
    for (int t = 0; t < kTT; ++t) {
      v2f z = {Dd * xv[t], 0.f};
      acc2[t] = z;
    }
#pragma unroll 4
    for (int n = 0; n < kN2; ++n) {
      float4 ac = ap[(long)n * kD];
      v2f a2 = {ac.x, ac.y};
      v2f cb2 = {ac.z, ac.w};
      v2f hn = h2[n];
#pragma unroll
      for (int t = 0; t < kTT; ++t) {
        v2f xx = {xv[t], xv[t]};
        hn = pkfma(hn, a2, xx);
        acc2[t] = pkfma(cb2, hn, acc2[t]);
      }
      h2[n] = hn;
    }
#pragma unroll
    for (int t = 0; t < kTT; ++t)
      yp[(long)(tt * kTT + t) * kD] = acc2[t].x + acc2[t].y;
  }
}

extern "C" void kernel_launch(void* const* d_in, const int* in_sizes, int n_in,
                              void* d_out, int out_size, void* d_ws, size_t ws_size,
                              hipStream_t stream) {
  const float* x      = (const float*)d_in[0];
  const float* log_dt = (const float*)d_in[1];
  const float* Bm     = (const float*)d_in[2];
  const float* Cm     = (const float*)d_in[3];
  const float* Dv     = (const float*)d_in[4];
  float* y = (float*)d_out;

  unsigned short* u = (unsigned short*)d_ws;
  float4* acb4 = (float4*)((char*)d_ws + kUBytes);        // 32*1024 float4
  float2* a2t  = (float2*)(acb4 + (long)kN2 * kD);        // 32*1024 float2
  float*  aTt  = (float*)(a2t + (long)kN2 * kD);          // 64*1024 float

  hipLaunchKernelGGL(s4d_coef_kernel, dim3((kN2 * kD) / 256), dim3(256), 0, stream,
                     log_dt, Bm, Cm, acb4, a2t, aTt);
  hipLaunchKernelGGL(s4d_state_kernel, dim3((kBatch * kC * kD) / 256), dim3(256), 0,
                     stream, x, a2t, u);
  hipLaunchKernelGGL(s4d_scan_kernel, dim3((kBatch * kN * kD) / 256), dim3(256), 0, stream,
                     aTt, u);
  hipLaunchKernelGGL(s4d_out_kernel, dim3((kBatch * kC * kD) / 256), dim3(256), 0, stream,
                     x, Dv, acb4, u, y);
}